// Round 19
// baseline (67.392 us; speedup 1.0000x reference)
//
#include <hip/hip_runtime.h>
#include <hip/hip_bf16.h>

typedef __attribute__((ext_vector_type(8))) short short8;
typedef __attribute__((ext_vector_type(4))) float f32x4;
typedef __attribute__((ext_vector_type(2))) float f32x2;

#define B_ 8
#define N_ 4096
#define E_ 16384
#define K_ 16
#define F_ 128

#if defined(__has_builtin)
#  if __has_builtin(__builtin_amdgcn_cvt_pk_f32_fp8) && __has_builtin(__builtin_amdgcn_cvt_pk_fp8_f32)
#    define HW_FP8 1
#  endif
#endif

__device__ __forceinline__ unsigned short f2bf(float f) {
    union { float f; unsigned int u; } c; c.f = f;
    unsigned int u = c.u;
    unsigned int r = (u + 0x7fffu + ((u >> 16) & 1u)) >> 16;
    return (unsigned short)r;
}
__device__ __forceinline__ float fast_tanh(float x) {
    float e = __expf(2.0f * x);
    return 1.0f - 2.0f / (e + 1.0f);
}

// ---- fp8 e4m3 codec (HW when available; matched manual encode/decode pair) ----
__device__ __forceinline__ unsigned int f2fp8_manual(float v) {
    unsigned int u = __float_as_uint(v * 0x1p-120f);
    unsigned int r = (u & 0x7fffffffu) + 0x7ffffu + ((u >> 20) & 1u);
    return ((r >> 20) & 0x7fu) | ((u >> 24) & 0x80u);
}
__device__ __forceinline__ unsigned int pack_fp8x4(float t0, float t1, float t2, float t3) {
#ifdef HW_FP8
    int wd = 0;
    wd = __builtin_amdgcn_cvt_pk_fp8_f32(t0, t1, wd, false);
    wd = __builtin_amdgcn_cvt_pk_fp8_f32(t2, t3, wd, true);
    return (unsigned int)wd;
#else
    return f2fp8_manual(t0) | (f2fp8_manual(t1) << 8) |
           (f2fp8_manual(t2) << 16) | (f2fp8_manual(t3) << 24);
#endif
}
#ifndef HW_FP8
#define DECM(bb) __int_as_float((int)((((bb) & 0x80u) << 24) | (((bb) & 0x7fu) << 20)))
#endif

// ---- detect whether an "integer" input buffer is int64 (high words all 0) ----
__device__ __forceinline__ int detect64(const int* raw) {
    int o = 0;
    #pragma unroll
    for (int i = 1; i < 128; i += 2) o |= raw[i];
    return (o == 0) ? 1 : 0;
}

// 17 blocks: [0,16) build wf (W1,W2 in MFMA fragment order, bf16);
// block 16: i64/i32 flags + zero the 16 per-group barrier counters.
__global__ void wprep(const float* __restrict__ W1, const float* __restrict__ W2,
                      const int* __restrict__ edges_raw, const int* __restrict__ ne_raw,
                      unsigned short* __restrict__ wf, int* __restrict__ flags) {
    int blk = blockIdx.x, tid = threadIdx.x;
    if (blk == 16) {
        if (tid == 0) {
            flags[0] = detect64(edges_raw);
            flags[1] = detect64(ne_raw);
        }
        if (tid < 16) flags[4 + tid] = 0;   // counters [4..20)
        return;
    }
    int gtid = blk * 256 + tid;    // 0..4095
    int wsel = gtid >> 11;
    int q = gtid & 2047;
    int lane = q & 63;
    int gq = q >> 6;
    int nt = gq >> 2, g = gq & 3;
    const float* W = wsel ? W2 : W1;
    int j = nt * 16 + (lane & 15);
    int kbase = g * 32 + 8 * (lane >> 4);
    unsigned short* d = wf + wsel * 16384 + q * 8;
    #pragma unroll
    for (int t = 0; t < 8; ++t) d[t] = f2bf(W[j * 128 + kbase + t]);
}

// per-group barrier: the 64 blocks with the same (blockIdx&7) sync.
// Relaxed atomics; __syncthreads (compiler emits full waitcnt before
// s_barrier) drains the block's stores into its XCD L2 before arrival;
// producer/consumer blocks share the group => same XCD L2.
// (Pattern validated on this harness in rounds 15 & 16.)
__device__ __forceinline__ void group_bar(int* c) {
    __syncthreads();
    if (threadIdx.x == 0) {
        __hip_atomic_fetch_add(c, 1, __ATOMIC_RELAXED, __HIP_MEMORY_SCOPE_AGENT);
        while (__hip_atomic_load(c, __ATOMIC_RELAXED, __HIP_MEMORY_SCOPE_AGENT) < 64) {
            __builtin_amdgcn_s_sleep(2);
        }
    }
    __syncthreads();
}

// MEGA: 512 blocks, block owns 64 consecutive nodes of batch (blk&7 group).
// phase 1: y1 = fp8(tanh(x0 @ W1^T + b1)) dense; + x0->out[:,0:128]; + sid2.
// phase 2: x1 = mean_k y1[sid2[n,k]] -> out[:,128:256] + LDS(bf16);
//          y2 = fp8(tanh(x1 @ W2^T + b2)) dense.
// phase 3: x2 = mean_k y2[sid2[n,k]] -> out[:,256:384].
__global__ void __launch_bounds__(256) mega_kernel(
    const float* __restrict__ x0, const int* __restrict__ edges_raw,
    const int* __restrict__ ne_raw, const int* __restrict__ mask,
    int* __restrict__ flags, const unsigned short* __restrict__ wf,
    const float* __restrict__ b1, const float* __restrict__ b2,
    unsigned char* __restrict__ y1, unsigned char* __restrict__ y2,
    int* __restrict__ sid2, float* __restrict__ out) {
    __shared__ short xt[64 * F_];   // 16 KB, chunk-swizzled
    int tid = threadIdx.x;
    int blk = blockIdx.x;
    int grp = blk & 7;
    int swz = grp * 64 + (blk >> 3);   // batch-per-XCD (512 blocks)
    int b = swz >> 6;
    int r0 = (swz & 63) * 64;          // first node row of this block
    int wid = tid >> 6, lane = tid & 63;
    int qt = lane >> 4, s16 = lane & 15;

    // ---------------- phase 1: node transform round 1 ----------------
    {   // sid2 pack: 4 coalesced entries/thread
        int s64e = flags[0], s64n = flags[1];
        int base = swz * 1024;         // 512 blocks x 1024 = B*N*K entries
        #pragma unroll
        for (int t = 0; t < 4; ++t) {
            int i = base + t * 256 + tid;
            int bb = i >> 16;          // batch of entry (N*K = 65536)
            int eid = s64n ? ne_raw[2 * (long long)i] : ne_raw[i];
            long long ei = (long long)(bb * E_ + eid);
            int s = s64e ? edges_raw[6 * ei] : edges_raw[3 * ei];
            sid2[i] = mask[i] ? s : -1;
        }
    }
    #pragma unroll
    for (int c = 0; c < 4; ++c) {       // stage 64 fp32 rows -> LDS bf16
        int ci = tid + 256 * c;         // 0..1023
        int row = ci >> 4, ch = ci & 15;
        int pch = ch ^ (row & 15);
        long long gnode = (long long)(b * N_ + r0 + row);
        const float* src = x0 + gnode * F_ + ch * 8;
        float4 v0 = *(const float4*)src;
        float4 v1 = *(const float4*)(src + 4);
        ushort4 h0, h1;
        h0.x = f2bf(v0.x); h0.y = f2bf(v0.y); h0.z = f2bf(v0.z); h0.w = f2bf(v0.w);
        h1.x = f2bf(v1.x); h1.y = f2bf(v1.y); h1.z = f2bf(v1.z); h1.w = f2bf(v1.w);
        *(ushort4*)&xt[row * F_ + pch * 8] = h0;
        *(ushort4*)&xt[row * F_ + pch * 8 + 4] = h1;
        float* od = out + gnode * 384 + ch * 8;   // x0 -> out[:,0:128]
        *(float4*)od = v0;
        *(float4*)(od + 4) = v1;
    }
    __syncthreads();
    {
        int rr = wid * 16 + (lane & 15);
        short8 bfr[4];
        #pragma unroll
        for (int g = 0; g < 4; ++g) {
            int pch = (g * 4 + (lane >> 4)) ^ (rr & 15);
            bfr[g] = *(const short8*)&xt[rr * F_ + pch * 8];
        }
        int jq = (lane >> 4) * 4;
        long long ybyte = ((long long)(b * N_ + r0 + wid * 16 + (lane & 15))) * F_;
        #pragma unroll
        for (int nt = 0; nt < 8; ++nt) {
            f32x4 acc = (f32x4){0.f, 0.f, 0.f, 0.f};
            #pragma unroll
            for (int g = 0; g < 4; ++g) {
                short8 afr = *(const short8*)(wf + ((nt * 4 + g) * 64 + lane) * 8);
                acc = __builtin_amdgcn_mfma_f32_16x16x32_bf16(afr, bfr[g], acc, 0, 0, 0);
            }
            float4 bv = *(const float4*)(b1 + nt * 16 + jq);
            float t0 = fast_tanh(acc[0] + bv.x);
            float t1 = fast_tanh(acc[1] + bv.y);
            float t2 = fast_tanh(acc[2] + bv.z);
            float t3 = fast_tanh(acc[3] + bv.w);
            *(unsigned int*)(y1 + ybyte + nt * 16 + jq) = pack_fp8x4(t0, t1, t2, t3);
        }
    }
    group_bar(flags + 4 + grp);

    // ---------------- phase 2: aggregate y1 -> x1, transform -> y2 ----------------
    {
        const unsigned char* ybase = y1 + (long long)b * (N_ * F_) + s16 * 8;
        #pragma unroll
        for (int t = 0; t < 4; ++t) {
            int row = wid * 16 + qt * 4 + t;
            long long gnode = (long long)(b * N_ + r0 + row);
            const int4* ip = (const int4*)(sid2 + gnode * K_);
            int4 i0 = ip[0], i1 = ip[1], i2 = ip[2], i3 = ip[3];
            float cnt = (float)((i0.x >= 0) + (i0.y >= 0) + (i0.z >= 0) + (i0.w >= 0) +
                                (i1.x >= 0) + (i1.y >= 0) + (i1.z >= 0) + (i1.w >= 0) +
                                (i2.x >= 0) + (i2.y >= 0) + (i2.z >= 0) + (i2.w >= 0) +
                                (i3.x >= 0) + (i3.y >= 0) + (i3.z >= 0) + (i3.w >= 0));
            float a0 = 0.f, a1 = 0.f, a2 = 0.f, a3 = 0.f;
            float a4 = 0.f, a5 = 0.f, a6 = 0.f, a7 = 0.f;
#ifdef HW_FP8
            #define PROC(pk) { \
                float m = ((pk) >= 0) ? 1.0f : 0.0f; \
                int nid = (pk) < 0 ? 0 : (pk); \
                uint2 v = *(const uint2*)(ybase + (long long)nid * F_); \
                f32x2 c0 = __builtin_amdgcn_cvt_pk_f32_fp8(v.x, false); \
                f32x2 c1 = __builtin_amdgcn_cvt_pk_f32_fp8(v.x, true); \
                f32x2 c2 = __builtin_amdgcn_cvt_pk_f32_fp8(v.y, false); \
                f32x2 c3 = __builtin_amdgcn_cvt_pk_f32_fp8(v.y, true); \
                a0 += m * c0.x; a1 += m * c0.y; a2 += m * c1.x; a3 += m * c1.y; \
                a4 += m * c2.x; a5 += m * c2.y; a6 += m * c3.x; a7 += m * c3.y; }
#else
            #define PROC(pk) { \
                float ms = ((pk) >= 0) ? 0x1p120f : 0.0f; \
                int nid = (pk) < 0 ? 0 : (pk); \
                uint2 v = *(const uint2*)(ybase + (long long)nid * F_); \
                a0 += ms * DECM(v.x); a1 += ms * DECM(v.x >> 8); \
                a2 += ms * DECM(v.x >> 16); a3 += ms * DECM(v.x >> 24); \
                a4 += ms * DECM(v.y); a5 += ms * DECM(v.y >> 8); \
                a6 += ms * DECM(v.y >> 16); a7 += ms * DECM(v.y >> 24); }
#endif
            PROC(i0.x) PROC(i0.y) PROC(i0.z) PROC(i0.w)
            PROC(i1.x) PROC(i1.y) PROC(i1.z) PROC(i1.w)
            PROC(i2.x) PROC(i2.y) PROC(i2.z) PROC(i2.w)
            PROC(i3.x) PROC(i3.y) PROC(i3.z) PROC(i3.w)
            #undef PROC
            float inv = 1.0f / (cnt + 1e-8f);
            a0 *= inv; a1 *= inv; a2 *= inv; a3 *= inv;
            a4 *= inv; a5 *= inv; a6 *= inv; a7 *= inv;
            float* po = out + gnode * 384 + 128 + s16 * 8;
            *(f32x4*)po = (f32x4){a0, a1, a2, a3};
            *(f32x4*)(po + 4) = (f32x4){a4, a5, a6, a7};
            int pch = s16 ^ (row & 15);
            short8 h;
            h[0] = (short)f2bf(a0); h[1] = (short)f2bf(a1);
            h[2] = (short)f2bf(a2); h[3] = (short)f2bf(a3);
            h[4] = (short)f2bf(a4); h[5] = (short)f2bf(a5);
            h[6] = (short)f2bf(a6); h[7] = (short)f2bf(a7);
            *(short8*)&xt[row * F_ + pch * 8] = h;
        }
        __syncthreads();
        int rr = wid * 16 + (lane & 15);
        short8 bfr[4];
        #pragma unroll
        for (int g = 0; g < 4; ++g) {
            int pch = (g * 4 + (lane >> 4)) ^ (rr & 15);
            bfr[g] = *(const short8*)&xt[rr * F_ + pch * 8];
        }
        int jq = (lane >> 4) * 4;
        long long ybyte = ((long long)(b * N_ + r0 + wid * 16 + (lane & 15))) * F_;
        #pragma unroll
        for (int nt = 0; nt < 8; ++nt) {
            f32x4 acc = (f32x4){0.f, 0.f, 0.f, 0.f};
            #pragma unroll
            for (int g = 0; g < 4; ++g) {
                short8 afr = *(const short8*)(wf + 16384 + ((nt * 4 + g) * 64 + lane) * 8);
                acc = __builtin_amdgcn_mfma_f32_16x16x32_bf16(afr, bfr[g], acc, 0, 0, 0);
            }
            float4 bv = *(const float4*)(b2 + nt * 16 + jq);
            float t0 = fast_tanh(acc[0] + bv.x);
            float t1 = fast_tanh(acc[1] + bv.y);
            float t2 = fast_tanh(acc[2] + bv.z);
            float t3 = fast_tanh(acc[3] + bv.w);
            *(unsigned int*)(y2 + ybyte + nt * 16 + jq) = pack_fp8x4(t0, t1, t2, t3);
        }
    }
    group_bar(flags + 12 + grp);

    // ---------------- phase 3: aggregate y2 -> x2 ----------------
    {
        const unsigned char* ybase = y2 + (long long)b * (N_ * F_) + s16 * 8;
        #pragma unroll
        for (int t = 0; t < 4; ++t) {
            int row = wid * 16 + qt * 4 + t;
            long long gnode = (long long)(b * N_ + r0 + row);
            const int4* ip = (const int4*)(sid2 + gnode * K_);
            int4 i0 = ip[0], i1 = ip[1], i2 = ip[2], i3 = ip[3];
            float cnt = (float)((i0.x >= 0) + (i0.y >= 0) + (i0.z >= 0) + (i0.w >= 0) +
                                (i1.x >= 0) + (i1.y >= 0) + (i1.z >= 0) + (i1.w >= 0) +
                                (i2.x >= 0) + (i2.y >= 0) + (i2.z >= 0) + (i2.w >= 0) +
                                (i3.x >= 0) + (i3.y >= 0) + (i3.z >= 0) + (i3.w >= 0));
            float a0 = 0.f, a1 = 0.f, a2 = 0.f, a3 = 0.f;
            float a4 = 0.f, a5 = 0.f, a6 = 0.f, a7 = 0.f;
#ifdef HW_FP8
            #define PROC(pk) { \
                float m = ((pk) >= 0) ? 1.0f : 0.0f; \
                int nid = (pk) < 0 ? 0 : (pk); \
                uint2 v = *(const uint2*)(ybase + (long long)nid * F_); \
                f32x2 c0 = __builtin_amdgcn_cvt_pk_f32_fp8(v.x, false); \
                f32x2 c1 = __builtin_amdgcn_cvt_pk_f32_fp8(v.x, true); \
                f32x2 c2 = __builtin_amdgcn_cvt_pk_f32_fp8(v.y, false); \
                f32x2 c3 = __builtin_amdgcn_cvt_pk_f32_fp8(v.y, true); \
                a0 += m * c0.x; a1 += m * c0.y; a2 += m * c1.x; a3 += m * c1.y; \
                a4 += m * c2.x; a5 += m * c2.y; a6 += m * c3.x; a7 += m * c3.y; }
#else
            #define PROC(pk) { \
                float ms = ((pk) >= 0) ? 0x1p120f : 0.0f; \
                int nid = (pk) < 0 ? 0 : (pk); \
                uint2 v = *(const uint2*)(ybase + (long long)nid * F_); \
                a0 += ms * DECM(v.x); a1 += ms * DECM(v.x >> 8); \
                a2 += ms * DECM(v.x >> 16); a3 += ms * DECM(v.x >> 24); \
                a4 += ms * DECM(v.y); a5 += ms * DECM(v.y >> 8); \
                a6 += ms * DECM(v.y >> 16); a7 += ms * DECM(v.y >> 24); }
#endif
            PROC(i0.x) PROC(i0.y) PROC(i0.z) PROC(i0.w)
            PROC(i1.x) PROC(i1.y) PROC(i1.z) PROC(i1.w)
            PROC(i2.x) PROC(i2.y) PROC(i2.z) PROC(i2.w)
            PROC(i3.x) PROC(i3.y) PROC(i3.z) PROC(i3.w)
            #undef PROC
            float inv = 1.0f / (cnt + 1e-8f);
            a0 *= inv; a1 *= inv; a2 *= inv; a3 *= inv;
            a4 *= inv; a5 *= inv; a6 *= inv; a7 *= inv;
            float* po = out + gnode * 384 + 256 + s16 * 8;
            *(f32x4*)po = (f32x4){a0, a1, a2, a3};
            *(f32x4*)(po + 4) = (f32x4){a4, a5, a6, a7};
        }
    }
}

extern "C" void kernel_launch(void* const* d_in, const int* in_sizes, int n_in,
                              void* d_out, int out_size, void* d_ws, size_t ws_size,
                              hipStream_t stream) {
    const float* x0        = (const float*)d_in[0];
    const int*   edges_raw = (const int*)d_in[1];
    const int*   ne_raw    = (const int*)d_in[2];
    const int*   mask      = (const int*)d_in[3];
    const float* W1        = (const float*)d_in[4];
    const float* b1        = (const float*)d_in[5];
    const float* W2        = (const float*)d_in[6];
    const float* b2        = (const float*)d_in[7];
    float* out = (float*)d_out;
    char* ws = (char*)d_ws;

    unsigned char*  y1   = (unsigned char*)ws;                    // B*N*F fp8 = 4 MB
    unsigned char*  y2   = (unsigned char*)(ws + 4194304);        // B*N*F fp8 = 4 MB
    unsigned short* wf   = (unsigned short*)(ws + 8388608);       // 2*128*128 = 64 KB
    int* flags           = (int*)(ws + 8454144);                  // flags + 16 counters
    int* sid2            = (int*)(ws + 8519680);                  // B*N*K     = 2 MB

    wprep<<<17, 256, 0, stream>>>(W1, W2, edges_raw, ne_raw, wf, flags);
    mega_kernel<<<512, 256, 0, stream>>>(x0, edges_raw, ne_raw, mask, flags,
                                         wf, b1, b2, y1, y2, sid2, out);
}

// Round 20
// 62.646 us; speedup vs baseline: 1.0758x; 1.0758x over previous
//
#include <hip/hip_runtime.h>
#include <hip/hip_bf16.h>

typedef __attribute__((ext_vector_type(8))) short short8;
typedef __attribute__((ext_vector_type(4))) float f32x4;
typedef __attribute__((ext_vector_type(2))) float f32x2;

#define B_ 8
#define N_ 4096
#define E_ 16384
#define K_ 16
#define F_ 128

#if defined(__has_builtin)
#  if __has_builtin(__builtin_amdgcn_cvt_pk_f32_fp8) && __has_builtin(__builtin_amdgcn_cvt_pk_fp8_f32)
#    define HW_FP8 1
#  endif
#endif

__device__ __forceinline__ unsigned short f2bf(float f) {
    union { float f; unsigned int u; } c; c.f = f;
    unsigned int u = c.u;
    unsigned int r = (u + 0x7fffu + ((u >> 16) & 1u)) >> 16;
    return (unsigned short)r;
}
__device__ __forceinline__ float fast_tanh(float x) {
    float e = __expf(2.0f * x);
    return 1.0f - 2.0f / (e + 1.0f);
}

// ---- fp8 e4m3 codec (HW when available; matched manual encode/decode pair) ----
__device__ __forceinline__ unsigned int f2fp8_manual(float v) {
    unsigned int u = __float_as_uint(v * 0x1p-120f);
    unsigned int r = (u & 0x7fffffffu) + 0x7ffffu + ((u >> 20) & 1u);
    return ((r >> 20) & 0x7fu) | ((u >> 24) & 0x80u);
}
__device__ __forceinline__ unsigned int pack_fp8x4(float t0, float t1, float t2, float t3) {
#ifdef HW_FP8
    int wd = 0;
    wd = __builtin_amdgcn_cvt_pk_fp8_f32(t0, t1, wd, false);
    wd = __builtin_amdgcn_cvt_pk_fp8_f32(t2, t3, wd, true);
    return (unsigned int)wd;
#else
    return f2fp8_manual(t0) | (f2fp8_manual(t1) << 8) |
           (f2fp8_manual(t2) << 16) | (f2fp8_manual(t3) << 24);
#endif
}
#ifndef HW_FP8
#define DECM(bb) __int_as_float((int)((((bb) & 0x80u) << 24) | (((bb) & 0x7fu) << 20)))
#endif

// ---- per-wave parallel int64 detect: lane i checks odd word 2i+1; all-zero
// high words across the first 64 entries => int64. One broadcast-cached load
// + one ballot (no serial thread-0 loop -- that was the r7 regression).
__device__ __forceinline__ int detect64_wave(const int* raw, int lane) {
    int w = raw[2 * lane + 1];
    unsigned long long bal = __ballot(w != 0);
    return (bal == 0) ? 1 : 0;
}

// load one MFMA A-fragment of W directly (replaces the wf precompute):
// frag(nt,g,lane) = bf16( W[(nt*16+(lane&15))*128 + g*32 + 8*(lane>>4) + t] )
__device__ __forceinline__ short8 wfrag(const float* __restrict__ W, int nt, int g, int lane) {
    const float* p = W + (nt * 16 + (lane & 15)) * 128 + g * 32 + 8 * (lane >> 4);
    float4 v0 = *(const float4*)p;
    float4 v1 = *(const float4*)(p + 4);
    short8 h;
    h[0] = (short)f2bf(v0.x); h[1] = (short)f2bf(v0.y);
    h[2] = (short)f2bf(v0.z); h[3] = (short)f2bf(v0.w);
    h[4] = (short)f2bf(v1.x); h[5] = (short)f2bf(v1.y);
    h[6] = (short)f2bf(v1.z); h[7] = (short)f2bf(v1.w);
    return h;
}

// Node transform round 1: y1[b,n,:] = fp8( tanh( x0[b,n,:] @ W1^T + b1 ) ), DENSE.
// Also: x0 -> out[:,0:128]; sid2[i] = mask[i] ? sender[ne[i]] : -1.
// 64 consecutive rows/block, 4 waves; W fragments loaded direct from W1.
__global__ void __launch_bounds__(256) node_kernel(
    const float* __restrict__ x0, const int* __restrict__ edges_raw,
    const int* __restrict__ ne_raw, const int* __restrict__ mask,
    const float* __restrict__ W1, const float* __restrict__ bias,
    unsigned char* __restrict__ y, float* __restrict__ out,
    int* __restrict__ sid2) {
    __shared__ short xt[64 * F_];   // 16 KB, chunk-swizzled
    int tid = threadIdx.x;
    int lane = tid & 63;
    int swz = (blockIdx.x & 7) * 64 + (blockIdx.x >> 3);   // batch-per-XCD (512 blocks)
    int b = swz >> 6;
    int r0 = (swz & 63) * 64;          // first node row of this block
    int s64e = detect64_wave(edges_raw, lane);
    int s64n = detect64_wave(ne_raw, lane);
    {                                  // sid2 pack: 4 coalesced entries/thread
        int base = swz * 1024;         // 512 blocks x 1024 = B*N*K entries
        #pragma unroll
        for (int t = 0; t < 4; ++t) {
            int i = base + t * 256 + tid;
            int bb = i >> 16;          // batch of entry (N*K = 65536)
            int eid = s64n ? ne_raw[2 * (long long)i] : ne_raw[i];
            long long ei = (long long)(bb * E_ + eid);
            int s = s64e ? edges_raw[6 * ei] : edges_raw[3 * ei];
            sid2[i] = mask[i] ? s : -1;
        }
    }
    // stage 64 consecutive fp32 rows into LDS as bf16; pch = ch^(row&15)
    #pragma unroll
    for (int c = 0; c < 4; ++c) {
        int ci = tid + 256 * c;         // 0..1023
        int row = ci >> 4, ch = ci & 15;
        int pch = ch ^ (row & 15);
        long long gnode = (long long)(b * N_ + r0 + row);
        const float* src = x0 + gnode * F_ + ch * 8;
        float4 v0 = *(const float4*)src;
        float4 v1 = *(const float4*)(src + 4);
        ushort4 h0, h1;
        h0.x = f2bf(v0.x); h0.y = f2bf(v0.y); h0.z = f2bf(v0.z); h0.w = f2bf(v0.w);
        h1.x = f2bf(v1.x); h1.y = f2bf(v1.y); h1.z = f2bf(v1.z); h1.w = f2bf(v1.w);
        *(ushort4*)&xt[row * F_ + pch * 8] = h0;
        *(ushort4*)&xt[row * F_ + pch * 8 + 4] = h1;
        float* od = out + gnode * 384 + ch * 8;   // x0 -> out[:,0:128]
        *(float4*)od = v0;
        *(float4*)(od + 4) = v1;
    }
    __syncthreads();
    int w = tid >> 6;
    int rr = w * 16 + (lane & 15);        // this wave's 16 node rows
    short8 bfr[4];
    #pragma unroll
    for (int g = 0; g < 4; ++g) {
        int pch = (g * 4 + (lane >> 4)) ^ (rr & 15);
        bfr[g] = *(const short8*)&xt[rr * F_ + pch * 8];
    }
    int jq = (lane >> 4) * 4;
    long long ybyte = ((long long)(b * N_ + r0 + w * 16 + (lane & 15))) * F_;
    #pragma unroll
    for (int nt = 0; nt < 8; ++nt) {
        f32x4 acc = (f32x4){0.f, 0.f, 0.f, 0.f};
        #pragma unroll
        for (int g = 0; g < 4; ++g) {
            short8 afr = wfrag(W1, nt, g, lane);
            acc = __builtin_amdgcn_mfma_f32_16x16x32_bf16(afr, bfr[g], acc, 0, 0, 0);
        }
        float4 bv = *(const float4*)(bias + nt * 16 + jq);
        float t0 = fast_tanh(acc[0] + bv.x);
        float t1 = fast_tanh(acc[1] + bv.y);
        float t2 = fast_tanh(acc[2] + bv.z);
        float t3 = fast_tanh(acc[3] + bv.w);
        *(unsigned int*)(y + ybyte + nt * 16 + jq) = pack_fp8x4(t0, t1, t2, t3);
    }
}

// FUSED agg1 + node2: block owns 64 consecutive nodes (r18-proven structure).
// Phase A: quarter (wid,qt) aggregates 4 nodes; lane owns 8 cols -> 64
//   independent 8B gathers in flight. x1 -> out[:,128:256] + LDS (bf16).
// Phase B: dense MFMA transform of the 64 x1 rows -> y2 (fp8), W2 direct.
__global__ void __launch_bounds__(256) aggnode_kernel(
    const unsigned char* __restrict__ y1, const int* __restrict__ sid2,
    const float* __restrict__ W2, const float* __restrict__ bias,
    float* __restrict__ out, unsigned char* __restrict__ y2) {
    __shared__ short xt[64 * F_];   // 16 KB
    int tid = threadIdx.x;
    int swz = (blockIdx.x & 7) * 64 + (blockIdx.x >> 3);   // batch-per-XCD (512 blocks)
    int b = swz >> 6;
    int r0 = (swz & 63) * 64;          // first node row of this block
    int wid = tid >> 6, lane = tid & 63;
    int qt = lane >> 4, s16 = lane & 15;
    const unsigned char* ybase = y1 + (long long)b * (N_ * F_) + s16 * 8;
    #pragma unroll
    for (int t = 0; t < 4; ++t) {
        int row = wid * 16 + qt * 4 + t;
        long long gnode = (long long)(b * N_ + r0 + row);
        const int4* ip = (const int4*)(sid2 + gnode * K_);
        int4 i0 = ip[0], i1 = ip[1], i2 = ip[2], i3 = ip[3];
        float cnt = (float)((i0.x >= 0) + (i0.y >= 0) + (i0.z >= 0) + (i0.w >= 0) +
                            (i1.x >= 0) + (i1.y >= 0) + (i1.z >= 0) + (i1.w >= 0) +
                            (i2.x >= 0) + (i2.y >= 0) + (i2.z >= 0) + (i2.w >= 0) +
                            (i3.x >= 0) + (i3.y >= 0) + (i3.z >= 0) + (i3.w >= 0));
        float a0 = 0.f, a1 = 0.f, a2 = 0.f, a3 = 0.f;
        float a4 = 0.f, a5 = 0.f, a6 = 0.f, a7 = 0.f;
#ifdef HW_FP8
        #define PROC(pk) { \
            float m = ((pk) >= 0) ? 1.0f : 0.0f; \
            int nid = (pk) < 0 ? 0 : (pk); \
            uint2 v = *(const uint2*)(ybase + (long long)nid * F_); \
            f32x2 c0 = __builtin_amdgcn_cvt_pk_f32_fp8(v.x, false); \
            f32x2 c1 = __builtin_amdgcn_cvt_pk_f32_fp8(v.x, true); \
            f32x2 c2 = __builtin_amdgcn_cvt_pk_f32_fp8(v.y, false); \
            f32x2 c3 = __builtin_amdgcn_cvt_pk_f32_fp8(v.y, true); \
            a0 += m * c0.x; a1 += m * c0.y; a2 += m * c1.x; a3 += m * c1.y; \
            a4 += m * c2.x; a5 += m * c2.y; a6 += m * c3.x; a7 += m * c3.y; }
#else
        #define PROC(pk) { \
            float ms = ((pk) >= 0) ? 0x1p120f : 0.0f; \
            int nid = (pk) < 0 ? 0 : (pk); \
            uint2 v = *(const uint2*)(ybase + (long long)nid * F_); \
            a0 += ms * DECM(v.x); a1 += ms * DECM(v.x >> 8); \
            a2 += ms * DECM(v.x >> 16); a3 += ms * DECM(v.x >> 24); \
            a4 += ms * DECM(v.y); a5 += ms * DECM(v.y >> 8); \
            a6 += ms * DECM(v.y >> 16); a7 += ms * DECM(v.y >> 24); }
#endif
        PROC(i0.x) PROC(i0.y) PROC(i0.z) PROC(i0.w)
        PROC(i1.x) PROC(i1.y) PROC(i1.z) PROC(i1.w)
        PROC(i2.x) PROC(i2.y) PROC(i2.z) PROC(i2.w)
        PROC(i3.x) PROC(i3.y) PROC(i3.z) PROC(i3.w)
        #undef PROC
        float inv = 1.0f / (cnt + 1e-8f);
        a0 *= inv; a1 *= inv; a2 *= inv; a3 *= inv;
        a4 *= inv; a5 *= inv; a6 *= inv; a7 *= inv;
        float* po = out + gnode * 384 + 128 + s16 * 8;
        *(f32x4*)po = (f32x4){a0, a1, a2, a3};
        *(f32x4*)(po + 4) = (f32x4){a4, a5, a6, a7};
        int pch = s16 ^ (row & 15);
        short8 h;
        h[0] = (short)f2bf(a0); h[1] = (short)f2bf(a1);
        h[2] = (short)f2bf(a2); h[3] = (short)f2bf(a3);
        h[4] = (short)f2bf(a4); h[5] = (short)f2bf(a5);
        h[6] = (short)f2bf(a6); h[7] = (short)f2bf(a7);
        *(short8*)&xt[row * F_ + pch * 8] = h;
    }
    __syncthreads();
    // phase B: dense transform of the 64 x1 rows -> y2 (W2 direct)
    int rr = wid * 16 + (lane & 15);
    short8 bfr[4];
    #pragma unroll
    for (int g = 0; g < 4; ++g) {
        int pch = (g * 4 + (lane >> 4)) ^ (rr & 15);
        bfr[g] = *(const short8*)&xt[rr * F_ + pch * 8];
    }
    int jq = (lane >> 4) * 4;
    long long ybyte = ((long long)(b * N_ + r0 + wid * 16 + (lane & 15))) * F_;
    #pragma unroll
    for (int nt = 0; nt < 8; ++nt) {
        f32x4 acc = (f32x4){0.f, 0.f, 0.f, 0.f};
        #pragma unroll
        for (int g = 0; g < 4; ++g) {
            short8 afr = wfrag(W2, nt, g, lane);
            acc = __builtin_amdgcn_mfma_f32_16x16x32_bf16(afr, bfr[g], acc, 0, 0, 0);
        }
        float4 bv = *(const float4*)(bias + nt * 16 + jq);
        float t0 = fast_tanh(acc[0] + bv.x);
        float t1 = fast_tanh(acc[1] + bv.y);
        float t2 = fast_tanh(acc[2] + bv.z);
        float t3 = fast_tanh(acc[3] + bv.w);
        *(unsigned int*)(y2 + ybyte + nt * 16 + jq) = pack_fp8x4(t0, t1, t2, t3);
    }
}

// final agg: x2[b,n,:] = ( sum_k y2[b, sid2[n,k], :] ) / (cnt + eps)
// ONE node per 16-lane quarter; 16 independent 8B gathers in flight.
__global__ void __launch_bounds__(256) agg_kernel(
    const unsigned char* __restrict__ y, const int* __restrict__ sid2,
    float* __restrict__ out, int col_off) {
    int tid = threadIdx.x;
    int swz = (blockIdx.x & 7) * 256 + (blockIdx.x >> 3);   // batch-per-XCD
    int nodeblk = swz * 16;            // 16 nodes per block
    int wid = tid >> 6, lane = tid & 63;
    int qt = lane >> 4, s16 = lane & 15;
    int node = nodeblk + wid * 4 + qt;
    int b = node >> 12;                // N=4096
    const int4* ip = (const int4*)(sid2 + node * K_);
    int4 i0 = ip[0], i1 = ip[1], i2 = ip[2], i3 = ip[3];
    float cnt = (float)((i0.x >= 0) + (i0.y >= 0) + (i0.z >= 0) + (i0.w >= 0) +
                        (i1.x >= 0) + (i1.y >= 0) + (i1.z >= 0) + (i1.w >= 0) +
                        (i2.x >= 0) + (i2.y >= 0) + (i2.z >= 0) + (i2.w >= 0) +
                        (i3.x >= 0) + (i3.y >= 0) + (i3.z >= 0) + (i3.w >= 0));
    const unsigned char* ybase = y + (long long)b * (N_ * F_) + s16 * 8;
    float a0 = 0.f, a1 = 0.f, a2 = 0.f, a3 = 0.f;
    float a4 = 0.f, a5 = 0.f, a6 = 0.f, a7 = 0.f;
#ifdef HW_FP8
    #define PROC(pk) { \
        float m = ((pk) >= 0) ? 1.0f : 0.0f; \
        int nid = (pk) < 0 ? 0 : (pk); \
        uint2 v = *(const uint2*)(ybase + (long long)nid * F_); \
        f32x2 c0 = __builtin_amdgcn_cvt_pk_f32_fp8(v.x, false); \
        f32x2 c1 = __builtin_amdgcn_cvt_pk_f32_fp8(v.x, true); \
        f32x2 c2 = __builtin_amdgcn_cvt_pk_f32_fp8(v.y, false); \
        f32x2 c3 = __builtin_amdgcn_cvt_pk_f32_fp8(v.y, true); \
        a0 += m * c0.x; a1 += m * c0.y; a2 += m * c1.x; a3 += m * c1.y; \
        a4 += m * c2.x; a5 += m * c2.y; a6 += m * c3.x; a7 += m * c3.y; }
#else
    #define PROC(pk) { \
        float ms = ((pk) >= 0) ? 0x1p120f : 0.0f; \
        int nid = (pk) < 0 ? 0 : (pk); \
        uint2 v = *(const uint2*)(ybase + (long long)nid * F_); \
        a0 += ms * DECM(v.x); a1 += ms * DECM(v.x >> 8); \
        a2 += ms * DECM(v.x >> 16); a3 += ms * DECM(v.x >> 24); \
        a4 += ms * DECM(v.y); a5 += ms * DECM(v.y >> 8); \
        a6 += ms * DECM(v.y >> 16); a7 += ms * DECM(v.y >> 24); }
#endif
    PROC(i0.x) PROC(i0.y) PROC(i0.z) PROC(i0.w)
    PROC(i1.x) PROC(i1.y) PROC(i1.z) PROC(i1.w)
    PROC(i2.x) PROC(i2.y) PROC(i2.z) PROC(i2.w)
    PROC(i3.x) PROC(i3.y) PROC(i3.z) PROC(i3.w)
    #undef PROC
    float inv = 1.0f / (cnt + 1e-8f);
    a0 *= inv; a1 *= inv; a2 *= inv; a3 *= inv;
    a4 *= inv; a5 *= inv; a6 *= inv; a7 *= inv;
    float* po = out + (long long)node * 384 + col_off + s16 * 8;
    *(f32x4*)po = (f32x4){a0, a1, a2, a3};
    *(f32x4*)(po + 4) = (f32x4){a4, a5, a6, a7};
}

extern "C" void kernel_launch(void* const* d_in, const int* in_sizes, int n_in,
                              void* d_out, int out_size, void* d_ws, size_t ws_size,
                              hipStream_t stream) {
    const float* x0        = (const float*)d_in[0];
    const int*   edges_raw = (const int*)d_in[1];
    const int*   ne_raw    = (const int*)d_in[2];
    const int*   mask      = (const int*)d_in[3];
    const float* W1        = (const float*)d_in[4];
    const float* b1        = (const float*)d_in[5];
    const float* W2        = (const float*)d_in[6];
    const float* b2        = (const float*)d_in[7];
    float* out = (float*)d_out;
    char* ws = (char*)d_ws;

    unsigned char*  y1   = (unsigned char*)ws;                    // B*N*F fp8 = 4 MB
    unsigned char*  y2   = (unsigned char*)(ws + 4194304);        // B*N*F fp8 = 4 MB
    int* sid2            = (int*)(ws + 8519680);                  // B*N*K     = 2 MB

    // round 1: dense node transform (+ x0 copy + sid2 pack)
    node_kernel<<<512, 256, 0, stream>>>(x0, edges_raw, ne_raw, mask,
                                         W1, b1, y1, out, sid2);
    // fused: aggregate y1 -> x1 (out[:,128:256] + LDS) -> transform -> y2
    aggnode_kernel<<<512, 256, 0, stream>>>(y1, sid2, W2, b2, out, y2);
    // final aggregation
    agg_kernel<<<2048, 256, 0, stream>>>(y2, sid2, out, 256);
}

// Round 21
// 46.638 us; speedup vs baseline: 1.4450x; 1.3432x over previous
//
#include <hip/hip_runtime.h>
#include <hip/hip_bf16.h>

typedef __attribute__((ext_vector_type(8))) short short8;
typedef __attribute__((ext_vector_type(4))) float f32x4;
typedef __attribute__((ext_vector_type(2))) float f32x2;

#define B_ 8
#define N_ 4096
#define E_ 16384
#define K_ 16
#define F_ 128

#if defined(__has_builtin)
#  if __has_builtin(__builtin_amdgcn_cvt_pk_f32_fp8) && __has_builtin(__builtin_amdgcn_cvt_pk_fp8_f32)
#    define HW_FP8 1
#  endif
#endif

__device__ __forceinline__ unsigned short f2bf(float f) {
    union { float f; unsigned int u; } c; c.f = f;
    unsigned int u = c.u;
    unsigned int r = (u + 0x7fffu + ((u >> 16) & 1u)) >> 16;
    return (unsigned short)r;
}
__device__ __forceinline__ float fast_tanh(float x) {
    float e = __expf(2.0f * x);
    return 1.0f - 2.0f / (e + 1.0f);
}

// ---- fp8 e4m3 codec (HW when available; matched manual encode/decode pair) ----
__device__ __forceinline__ unsigned int f2fp8_manual(float v) {
    unsigned int u = __float_as_uint(v * 0x1p-120f);
    unsigned int r = (u & 0x7fffffffu) + 0x7ffffu + ((u >> 20) & 1u);
    return ((r >> 20) & 0x7fu) | ((u >> 24) & 0x80u);
}
__device__ __forceinline__ unsigned int pack_fp8x4(float t0, float t1, float t2, float t3) {
#ifdef HW_FP8
    int wd = 0;
    wd = __builtin_amdgcn_cvt_pk_fp8_f32(t0, t1, wd, false);
    wd = __builtin_amdgcn_cvt_pk_fp8_f32(t2, t3, wd, true);
    return (unsigned int)wd;
#else
    return f2fp8_manual(t0) | (f2fp8_manual(t1) << 8) |
           (f2fp8_manual(t2) << 16) | (f2fp8_manual(t3) << 24);
#endif
}
#ifndef HW_FP8
#define DECM(bb) __int_as_float((int)((((bb) & 0x80u) << 24) | (((bb) & 0x7fu) << 20)))
#endif

// ---- detect whether an "integer" input buffer is int64 (high words all 0) ----
__device__ __forceinline__ int detect64(const int* raw) {
    int o = 0;
    #pragma unroll
    for (int i = 1; i < 128; i += 2) o |= raw[i];
    return (o == 0) ? 1 : 0;
}

// 17 blocks: [0,16) build wf (W1,W2 in MFMA fragment order, bf16);
// block 16: i64/i32 flags.
//   wf[((nt*4+g)*64+l)*8+t] = W[nt*16+(l&15)][g*32+8*(l>>4)+t]
__global__ void wprep(const float* __restrict__ W1, const float* __restrict__ W2,
                      const int* __restrict__ edges_raw, const int* __restrict__ ne_raw,
                      unsigned short* __restrict__ wf, int* __restrict__ flags) {
    int blk = blockIdx.x, tid = threadIdx.x;
    if (blk == 16) {
        if (tid == 0) {
            flags[0] = detect64(edges_raw);
            flags[1] = detect64(ne_raw);
        }
        return;
    }
    int gtid = blk * 256 + tid;    // 0..4095
    int wsel = gtid >> 11;
    int q = gtid & 2047;
    int lane = q & 63;
    int gq = q >> 6;
    int nt = gq >> 2, g = gq & 3;
    const float* W = wsel ? W2 : W1;
    int j = nt * 16 + (lane & 15);
    int kbase = g * 32 + 8 * (lane >> 4);
    unsigned short* d = wf + wsel * 16384 + q * 8;
    #pragma unroll
    for (int t = 0; t < 8; ++t) d[t] = f2bf(W[j * 128 + kbase + t]);
}

// Node transform round 1: y[b,n,:] = fp8( tanh( x0[b,n,:] @ W1^T + b1 ) ), DENSE.
// Also: copy x0 -> out[:,0:128] and pack sid2[i] = mask[i] ? sender[ne[i]] : -1.
// 64 consecutive rows/block, 4 waves, A=W (from wf), B=x^T.
__global__ void __launch_bounds__(256) node_kernel(
    const float* __restrict__ xsrc, const int* __restrict__ edges_raw,
    const int* __restrict__ ne_raw, const int* __restrict__ mask,
    const int* __restrict__ flags, const unsigned short* __restrict__ wf,
    const float* __restrict__ bias, unsigned char* __restrict__ y,
    float* __restrict__ out, int* __restrict__ sid2) {
    __shared__ short xt[64 * F_];   // 16 KB, chunk-swizzled
    int tid = threadIdx.x;
    int swz = (blockIdx.x & 7) * 64 + (blockIdx.x >> 3);   // batch-per-XCD (512 blocks)
    int b = swz >> 6;
    int r0 = (swz & 63) * 64;          // first node row of this block
    {                                  // sid2 pack: 4 coalesced entries/thread
        int s64e = flags[0], s64n = flags[1];
        int base = swz * 1024;         // 512 blocks x 1024 = B*N*K entries
        #pragma unroll
        for (int t = 0; t < 4; ++t) {
            int i = base + t * 256 + tid;
            int bb = i >> 16;          // batch of entry (N*K = 65536)
            int eid = s64n ? ne_raw[2 * (long long)i] : ne_raw[i];
            long long ei = (long long)(bb * E_ + eid);
            int s = s64e ? edges_raw[6 * ei] : edges_raw[3 * ei];
            sid2[i] = mask[i] ? s : -1;
        }
    }
    // stage 64 consecutive fp32 rows into LDS as bf16; pch = ch^(row&15)
    #pragma unroll
    for (int c = 0; c < 4; ++c) {
        int ci = tid + 256 * c;         // 0..1023
        int row = ci >> 4, ch = ci & 15;
        int pch = ch ^ (row & 15);
        long long gnode = (long long)(b * N_ + r0 + row);
        const float* src = xsrc + gnode * F_ + ch * 8;
        float4 v0 = *(const float4*)src;
        float4 v1 = *(const float4*)(src + 4);
        ushort4 h0, h1;
        h0.x = f2bf(v0.x); h0.y = f2bf(v0.y); h0.z = f2bf(v0.z); h0.w = f2bf(v0.w);
        h1.x = f2bf(v1.x); h1.y = f2bf(v1.y); h1.z = f2bf(v1.z); h1.w = f2bf(v1.w);
        *(ushort4*)&xt[row * F_ + pch * 8] = h0;
        *(ushort4*)&xt[row * F_ + pch * 8 + 4] = h1;
        float* od = out + gnode * 384 + ch * 8;   // x0 -> out[:,0:128]
        *(float4*)od = v0;
        *(float4*)(od + 4) = v1;
    }
    __syncthreads();
    int w = tid >> 6, lane = tid & 63;
    int rr = w * 16 + (lane & 15);        // this wave's 16 node rows
    short8 bfr[4];
    #pragma unroll
    for (int g = 0; g < 4; ++g) {
        int pch = (g * 4 + (lane >> 4)) ^ (rr & 15);
        bfr[g] = *(const short8*)&xt[rr * F_ + pch * 8];
    }
    int jq = (lane >> 4) * 4;
    long long ybyte = ((long long)(b * N_ + r0 + w * 16 + (lane & 15))) * F_;
    #pragma unroll
    for (int nt = 0; nt < 8; ++nt) {
        f32x4 acc = (f32x4){0.f, 0.f, 0.f, 0.f};
        #pragma unroll
        for (int g = 0; g < 4; ++g) {
            short8 afr = *(const short8*)(wf + ((nt * 4 + g) * 64 + lane) * 8);
            acc = __builtin_amdgcn_mfma_f32_16x16x32_bf16(afr, bfr[g], acc, 0, 0, 0);
        }
        float4 bv = *(const float4*)(bias + nt * 16 + jq);
        float t0 = fast_tanh(acc[0] + bv.x);
        float t1 = fast_tanh(acc[1] + bv.y);
        float t2 = fast_tanh(acc[2] + bv.z);
        float t3 = fast_tanh(acc[3] + bv.w);
        *(unsigned int*)(y + ybyte + nt * 16 + jq) = pack_fp8x4(t0, t1, t2, t3);
    }
}

// FUSED agg1 + node2: block owns 64 consecutive nodes.
// Phase A (agg): quarter (wid,qt) aggregates 4 nodes (rows wid*16+qt*4+t);
//   lane owns 8 cols -> 64 independent 8B gathers in flight per lane.
//   x1 row -> out[:,128:256] (fp32) AND directly into the LDS MFMA tile (bf16).
// Phase B (node2): dense MFMA transform of the 64 x1 rows -> y2 (fp8).
__global__ void __launch_bounds__(256) aggnode_kernel(
    const unsigned char* __restrict__ y1, const int* __restrict__ sid2,
    const unsigned short* __restrict__ wf2, const float* __restrict__ bias,
    float* __restrict__ out, unsigned char* __restrict__ y2) {
    __shared__ short xt[64 * F_];   // 16 KB
    int tid = threadIdx.x;
    int swz = (blockIdx.x & 7) * 64 + (blockIdx.x >> 3);   // batch-per-XCD (512 blocks)
    int b = swz >> 6;
    int r0 = (swz & 63) * 64;          // first node row of this block
    int wid = tid >> 6, lane = tid & 63;
    int qt = lane >> 4, s16 = lane & 15;
    const unsigned char* ybase = y1 + (long long)b * (N_ * F_) + s16 * 8;
    #pragma unroll
    for (int t = 0; t < 4; ++t) {
        int row = wid * 16 + qt * 4 + t;
        long long gnode = (long long)(b * N_ + r0 + row);
        const int4* ip = (const int4*)(sid2 + gnode * K_);
        int4 i0 = ip[0], i1 = ip[1], i2 = ip[2], i3 = ip[3];
        float cnt = (float)((i0.x >= 0) + (i0.y >= 0) + (i0.z >= 0) + (i0.w >= 0) +
                            (i1.x >= 0) + (i1.y >= 0) + (i1.z >= 0) + (i1.w >= 0) +
                            (i2.x >= 0) + (i2.y >= 0) + (i2.z >= 0) + (i2.w >= 0) +
                            (i3.x >= 0) + (i3.y >= 0) + (i3.z >= 0) + (i3.w >= 0));
        float a0 = 0.f, a1 = 0.f, a2 = 0.f, a3 = 0.f;
        float a4 = 0.f, a5 = 0.f, a6 = 0.f, a7 = 0.f;
#ifdef HW_FP8
        #define PROC(pk) { \
            float m = ((pk) >= 0) ? 1.0f : 0.0f; \
            int nid = (pk) < 0 ? 0 : (pk); \
            uint2 v = *(const uint2*)(ybase + (long long)nid * F_); \
            f32x2 c0 = __builtin_amdgcn_cvt_pk_f32_fp8(v.x, false); \
            f32x2 c1 = __builtin_amdgcn_cvt_pk_f32_fp8(v.x, true); \
            f32x2 c2 = __builtin_amdgcn_cvt_pk_f32_fp8(v.y, false); \
            f32x2 c3 = __builtin_amdgcn_cvt_pk_f32_fp8(v.y, true); \
            a0 += m * c0.x; a1 += m * c0.y; a2 += m * c1.x; a3 += m * c1.y; \
            a4 += m * c2.x; a5 += m * c2.y; a6 += m * c3.x; a7 += m * c3.y; }
#else
        #define PROC(pk) { \
            float ms = ((pk) >= 0) ? 0x1p120f : 0.0f; \
            int nid = (pk) < 0 ? 0 : (pk); \
            uint2 v = *(const uint2*)(ybase + (long long)nid * F_); \
            a0 += ms * DECM(v.x); a1 += ms * DECM(v.x >> 8); \
            a2 += ms * DECM(v.x >> 16); a3 += ms * DECM(v.x >> 24); \
            a4 += ms * DECM(v.y); a5 += ms * DECM(v.y >> 8); \
            a6 += ms * DECM(v.y >> 16); a7 += ms * DECM(v.y >> 24); }
#endif
        PROC(i0.x) PROC(i0.y) PROC(i0.z) PROC(i0.w)
        PROC(i1.x) PROC(i1.y) PROC(i1.z) PROC(i1.w)
        PROC(i2.x) PROC(i2.y) PROC(i2.z) PROC(i2.w)
        PROC(i3.x) PROC(i3.y) PROC(i3.z) PROC(i3.w)
        #undef PROC
        float inv = 1.0f / (cnt + 1e-8f);
        a0 *= inv; a1 *= inv; a2 *= inv; a3 *= inv;
        a4 *= inv; a5 *= inv; a6 *= inv; a7 *= inv;
        float* po = out + gnode * 384 + 128 + s16 * 8;
        *(f32x4*)po = (f32x4){a0, a1, a2, a3};
        *(f32x4*)(po + 4) = (f32x4){a4, a5, a6, a7};
        // x1 (bf16) straight into the MFMA staging tile; chunk = s16
        int pch = s16 ^ (row & 15);
        short8 h;
        h[0] = (short)f2bf(a0); h[1] = (short)f2bf(a1);
        h[2] = (short)f2bf(a2); h[3] = (short)f2bf(a3);
        h[4] = (short)f2bf(a4); h[5] = (short)f2bf(a5);
        h[6] = (short)f2bf(a6); h[7] = (short)f2bf(a7);
        *(short8*)&xt[row * F_ + pch * 8] = h;
    }
    __syncthreads();
    // phase B: dense transform of the 64 x1 rows -> y2
    int rr = wid * 16 + (lane & 15);
    short8 bfr[4];
    #pragma unroll
    for (int g = 0; g < 4; ++g) {
        int pch = (g * 4 + (lane >> 4)) ^ (rr & 15);
        bfr[g] = *(const short8*)&xt[rr * F_ + pch * 8];
    }
    int jq = (lane >> 4) * 4;
    long long ybyte = ((long long)(b * N_ + r0 + wid * 16 + (lane & 15))) * F_;
    #pragma unroll
    for (int nt = 0; nt < 8; ++nt) {
        f32x4 acc = (f32x4){0.f, 0.f, 0.f, 0.f};
        #pragma unroll
        for (int g = 0; g < 4; ++g) {
            short8 afr = *(const short8*)(wf2 + ((nt * 4 + g) * 64 + lane) * 8);
            acc = __builtin_amdgcn_mfma_f32_16x16x32_bf16(afr, bfr[g], acc, 0, 0, 0);
        }
        float4 bv = *(const float4*)(bias + nt * 16 + jq);
        float t0 = fast_tanh(acc[0] + bv.x);
        float t1 = fast_tanh(acc[1] + bv.y);
        float t2 = fast_tanh(acc[2] + bv.z);
        float t3 = fast_tanh(acc[3] + bv.w);
        *(unsigned int*)(y2 + ybyte + nt * 16 + jq) = pack_fp8x4(t0, t1, t2, t3);
    }
}

// final agg: x2[b,n,:] = ( sum_k y2[b, sid2[n,k], :] ) / (cnt + eps)
// ONE node per 16-lane quarter; 16 independent 8B gathers in flight.
__global__ void __launch_bounds__(256) agg_kernel(
    const unsigned char* __restrict__ y, const int* __restrict__ sid2,
    float* __restrict__ out, int col_off) {
    int tid = threadIdx.x;
    int swz = (blockIdx.x & 7) * 256 + (blockIdx.x >> 3);   // batch-per-XCD
    int nodeblk = swz * 16;            // 16 nodes per block
    int wid = tid >> 6, lane = tid & 63;
    int qt = lane >> 4, s16 = lane & 15;
    int node = nodeblk + wid * 4 + qt;
    int b = node >> 12;                // N=4096
    const int4* ip = (const int4*)(sid2 + node * K_);
    int4 i0 = ip[0], i1 = ip[1], i2 = ip[2], i3 = ip[3];
    float cnt = (float)((i0.x >= 0) + (i0.y >= 0) + (i0.z >= 0) + (i0.w >= 0) +
                        (i1.x >= 0) + (i1.y >= 0) + (i1.z >= 0) + (i1.w >= 0) +
                        (i2.x >= 0) + (i2.y >= 0) + (i2.z >= 0) + (i2.w >= 0) +
                        (i3.x >= 0) + (i3.y >= 0) + (i3.z >= 0) + (i3.w >= 0));
    const unsigned char* ybase = y + (long long)b * (N_ * F_) + s16 * 8;
    float a0 = 0.f, a1 = 0.f, a2 = 0.f, a3 = 0.f;
    float a4 = 0.f, a5 = 0.f, a6 = 0.f, a7 = 0.f;
#ifdef HW_FP8
    #define PROC(pk) { \
        float m = ((pk) >= 0) ? 1.0f : 0.0f; \
        int nid = (pk) < 0 ? 0 : (pk); \
        uint2 v = *(const uint2*)(ybase + (long long)nid * F_); \
        f32x2 c0 = __builtin_amdgcn_cvt_pk_f32_fp8(v.x, false); \
        f32x2 c1 = __builtin_amdgcn_cvt_pk_f32_fp8(v.x, true); \
        f32x2 c2 = __builtin_amdgcn_cvt_pk_f32_fp8(v.y, false); \
        f32x2 c3 = __builtin_amdgcn_cvt_pk_f32_fp8(v.y, true); \
        a0 += m * c0.x; a1 += m * c0.y; a2 += m * c1.x; a3 += m * c1.y; \
        a4 += m * c2.x; a5 += m * c2.y; a6 += m * c3.x; a7 += m * c3.y; }
#else
    #define PROC(pk) { \
        float ms = ((pk) >= 0) ? 0x1p120f : 0.0f; \
        int nid = (pk) < 0 ? 0 : (pk); \
        uint2 v = *(const uint2*)(ybase + (long long)nid * F_); \
        a0 += ms * DECM(v.x); a1 += ms * DECM(v.x >> 8); \
        a2 += ms * DECM(v.x >> 16); a3 += ms * DECM(v.x >> 24); \
        a4 += ms * DECM(v.y); a5 += ms * DECM(v.y >> 8); \
        a6 += ms * DECM(v.y >> 16); a7 += ms * DECM(v.y >> 24); }
#endif
    PROC(i0.x) PROC(i0.y) PROC(i0.z) PROC(i0.w)
    PROC(i1.x) PROC(i1.y) PROC(i1.z) PROC(i1.w)
    PROC(i2.x) PROC(i2.y) PROC(i2.z) PROC(i2.w)
    PROC(i3.x) PROC(i3.y) PROC(i3.z) PROC(i3.w)
    #undef PROC
    float inv = 1.0f / (cnt + 1e-8f);
    a0 *= inv; a1 *= inv; a2 *= inv; a3 *= inv;
    a4 *= inv; a5 *= inv; a6 *= inv; a7 *= inv;
    float* po = out + (long long)node * 384 + col_off + s16 * 8;
    *(f32x4*)po = (f32x4){a0, a1, a2, a3};
    *(f32x4*)(po + 4) = (f32x4){a4, a5, a6, a7};
}

extern "C" void kernel_launch(void* const* d_in, const int* in_sizes, int n_in,
                              void* d_out, int out_size, void* d_ws, size_t ws_size,
                              hipStream_t stream) {
    const float* x0        = (const float*)d_in[0];
    const int*   edges_raw = (const int*)d_in[1];
    const int*   ne_raw    = (const int*)d_in[2];
    const int*   mask      = (const int*)d_in[3];
    const float* W1        = (const float*)d_in[4];
    const float* b1        = (const float*)d_in[5];
    const float* W2        = (const float*)d_in[6];
    const float* b2        = (const float*)d_in[7];
    float* out = (float*)d_out;
    char* ws = (char*)d_ws;

    unsigned char*  y1   = (unsigned char*)ws;                    // B*N*F fp8 = 4 MB
    unsigned char*  y2   = (unsigned char*)(ws + 4194304);        // B*N*F fp8 = 4 MB
    unsigned short* wf   = (unsigned short*)(ws + 8388608);       // 2*128*128 = 64 KB
    int* flags           = (int*)(ws + 8454144);                  // 2 x int32
    int* sid2            = (int*)(ws + 8519680);                  // B*N*K     = 2 MB

    wprep<<<17, 256, 0, stream>>>(W1, W2, edges_raw, ne_raw, wf, flags);
    // round 1: dense node transform (+ x0 copy + sid2 pack)
    node_kernel<<<512, 256, 0, stream>>>(x0, edges_raw, ne_raw, mask,
                                         flags, wf, b1, y1, out, sid2);
    // fused: aggregate y1 -> x1 (out[:,128:256] + LDS) -> transform -> y2
    aggnode_kernel<<<512, 256, 0, stream>>>(y1, sid2, wf + 16384, b2, out, y2);
    // final aggregation
    agg_kernel<<<2048, 256, 0, stream>>>(y2, sid2, out, 256);
}

// Round 22
// 46.556 us; speedup vs baseline: 1.4476x; 1.0018x over previous
//
#include <hip/hip_runtime.h>
#include <hip/hip_bf16.h>

typedef __attribute__((ext_vector_type(8))) short short8;
typedef __attribute__((ext_vector_type(4))) float f32x4;
typedef __attribute__((ext_vector_type(2))) float f32x2;

#define B_ 8
#define N_ 4096
#define E_ 16384
#define K_ 16
#define F_ 128

#if defined(__has_builtin)
#  if __has_builtin(__builtin_amdgcn_cvt_pk_f32_fp8) && __has_builtin(__builtin_amdgcn_cvt_pk_fp8_f32)
#    define HW_FP8 1
#  endif
#endif

__device__ __forceinline__ unsigned short f2bf(float f) {
    union { float f; unsigned int u; } c; c.f = f;
    unsigned int u = c.u;
    unsigned int r = (u + 0x7fffu + ((u >> 16) & 1u)) >> 16;
    return (unsigned short)r;
}
__device__ __forceinline__ float fast_tanh(float x) {
    float e = __expf(2.0f * x);
    return 1.0f - 2.0f / (e + 1.0f);
}

// ---- fp8 e4m3 codec (HW when available; matched manual encode/decode pair) ----
__device__ __forceinline__ unsigned int f2fp8_manual(float v) {
    unsigned int u = __float_as_uint(v * 0x1p-120f);
    unsigned int r = (u & 0x7fffffffu) + 0x7ffffu + ((u >> 20) & 1u);
    return ((r >> 20) & 0x7fu) | ((u >> 24) & 0x80u);
}
__device__ __forceinline__ unsigned int pack_fp8x4(float t0, float t1, float t2, float t3) {
#ifdef HW_FP8
    int wd = 0;
    wd = __builtin_amdgcn_cvt_pk_fp8_f32(t0, t1, wd, false);
    wd = __builtin_amdgcn_cvt_pk_fp8_f32(t2, t3, wd, true);
    return (unsigned int)wd;
#else
    return f2fp8_manual(t0) | (f2fp8_manual(t1) << 8) |
           (f2fp8_manual(t2) << 16) | (f2fp8_manual(t3) << 24);
#endif
}
#ifndef HW_FP8
#define DECM(bb) __int_as_float((int)((((bb) & 0x80u) << 24) | (((bb) & 0x7fu) << 20)))
#endif

// ---- detect whether an "integer" input buffer is int64 (high words all 0) ----
__device__ __forceinline__ int detect64(const int* raw) {
    int o = 0;
    #pragma unroll
    for (int i = 1; i < 128; i += 2) o |= raw[i];
    return (o == 0) ? 1 : 0;
}

// 17 blocks: [0,16) build wf (W1,W2 in MFMA fragment order, bf16);
// block 16: i64/i32 flags.
//   wf[((nt*4+g)*64+l)*8+t] = W[nt*16+(l&15)][g*32+8*(l>>4)+t]
__global__ void wprep(const float* __restrict__ W1, const float* __restrict__ W2,
                      const int* __restrict__ edges_raw, const int* __restrict__ ne_raw,
                      unsigned short* __restrict__ wf, int* __restrict__ flags) {
    int blk = blockIdx.x, tid = threadIdx.x;
    if (blk == 16) {
        if (tid == 0) {
            flags[0] = detect64(edges_raw);
            flags[1] = detect64(ne_raw);
        }
        return;
    }
    int gtid = blk * 256 + tid;    // 0..4095
    int wsel = gtid >> 11;
    int q = gtid & 2047;
    int lane = q & 63;
    int gq = q >> 6;
    int nt = gq >> 2, g = gq & 3;
    const float* W = wsel ? W2 : W1;
    int j = nt * 16 + (lane & 15);
    int kbase = g * 32 + 8 * (lane >> 4);
    unsigned short* d = wf + wsel * 16384 + q * 8;
    #pragma unroll
    for (int t = 0; t < 8; ++t) d[t] = f2bf(W[j * 128 + kbase + t]);
}

// Node transform round 1: y[b,n,:] = fp8( tanh( x0[b,n,:] @ W1^T + b1 ) ), DENSE.
// Also: copy x0 -> out[:,0:128] and pack sid2[i] = mask[i] ? sender[ne[i]] : -1.
// 64 consecutive rows/block, 4 waves, A=W (from wf), B=x^T.
__global__ void __launch_bounds__(256) node_kernel(
    const float* __restrict__ xsrc, const int* __restrict__ edges_raw,
    const int* __restrict__ ne_raw, const int* __restrict__ mask,
    const int* __restrict__ flags, const unsigned short* __restrict__ wf,
    const float* __restrict__ bias, unsigned char* __restrict__ y,
    float* __restrict__ out, int* __restrict__ sid2) {
    __shared__ short xt[64 * F_];   // 16 KB, chunk-swizzled
    int tid = threadIdx.x;
    int swz = (blockIdx.x & 7) * 64 + (blockIdx.x >> 3);   // batch-per-XCD (512 blocks)
    int b = swz >> 6;
    int r0 = (swz & 63) * 64;          // first node row of this block
    {                                  // sid2 pack: 4 coalesced entries/thread
        int s64e = flags[0], s64n = flags[1];
        int base = swz * 1024;         // 512 blocks x 1024 = B*N*K entries
        #pragma unroll
        for (int t = 0; t < 4; ++t) {
            int i = base + t * 256 + tid;
            int bb = i >> 16;          // batch of entry (N*K = 65536)
            int eid = s64n ? ne_raw[2 * (long long)i] : ne_raw[i];
            long long ei = (long long)(bb * E_ + eid);
            int s = s64e ? edges_raw[6 * ei] : edges_raw[3 * ei];
            sid2[i] = mask[i] ? s : -1;
        }
    }
    // stage 64 consecutive fp32 rows into LDS as bf16; pch = ch^(row&15)
    #pragma unroll
    for (int c = 0; c < 4; ++c) {
        int ci = tid + 256 * c;         // 0..1023
        int row = ci >> 4, ch = ci & 15;
        int pch = ch ^ (row & 15);
        long long gnode = (long long)(b * N_ + r0 + row);
        const float* src = xsrc + gnode * F_ + ch * 8;
        float4 v0 = *(const float4*)src;
        float4 v1 = *(const float4*)(src + 4);
        ushort4 h0, h1;
        h0.x = f2bf(v0.x); h0.y = f2bf(v0.y); h0.z = f2bf(v0.z); h0.w = f2bf(v0.w);
        h1.x = f2bf(v1.x); h1.y = f2bf(v1.y); h1.z = f2bf(v1.z); h1.w = f2bf(v1.w);
        *(ushort4*)&xt[row * F_ + pch * 8] = h0;
        *(ushort4*)&xt[row * F_ + pch * 8 + 4] = h1;
        float* od = out + gnode * 384 + ch * 8;   // x0 -> out[:,0:128]
        *(float4*)od = v0;
        *(float4*)(od + 4) = v1;
    }
    __syncthreads();
    int w = tid >> 6, lane = tid & 63;
    int rr = w * 16 + (lane & 15);        // this wave's 16 node rows
    short8 bfr[4];
    #pragma unroll
    for (int g = 0; g < 4; ++g) {
        int pch = (g * 4 + (lane >> 4)) ^ (rr & 15);
        bfr[g] = *(const short8*)&xt[rr * F_ + pch * 8];
    }
    int jq = (lane >> 4) * 4;
    long long ybyte = ((long long)(b * N_ + r0 + w * 16 + (lane & 15))) * F_;
    #pragma unroll
    for (int nt = 0; nt < 8; ++nt) {
        f32x4 acc = (f32x4){0.f, 0.f, 0.f, 0.f};
        #pragma unroll
        for (int g = 0; g < 4; ++g) {
            short8 afr = *(const short8*)(wf + ((nt * 4 + g) * 64 + lane) * 8);
            acc = __builtin_amdgcn_mfma_f32_16x16x32_bf16(afr, bfr[g], acc, 0, 0, 0);
        }
        float4 bv = *(const float4*)(bias + nt * 16 + jq);
        float t0 = fast_tanh(acc[0] + bv.x);
        float t1 = fast_tanh(acc[1] + bv.y);
        float t2 = fast_tanh(acc[2] + bv.z);
        float t3 = fast_tanh(acc[3] + bv.w);
        *(unsigned int*)(y + ybyte + nt * 16 + jq) = pack_fp8x4(t0, t1, t2, t3);
    }
}

// FUSED agg1 + node2, HIGH-TLP shape: 2048 blocks, 16 nodes/block.
// Phase A: one node per 16-lane quarter (proven agg structure, full-device
//   TLP); x1 -> out[:,128:256] (fp32) AND a 16x128 bf16 LDS tile.
// Phase B: wave 0 alone transforms the 16 x1 rows -> y2 (fp8); waves 1-3
//   return after the barrier.
__global__ void __launch_bounds__(256) aggnode_kernel(
    const unsigned char* __restrict__ y1, const int* __restrict__ sid2,
    const unsigned short* __restrict__ wf2, const float* __restrict__ bias,
    float* __restrict__ out, unsigned char* __restrict__ y2) {
    __shared__ short xt[16 * F_];   // 4 KB
    int tid = threadIdx.x;
    int swz = (blockIdx.x & 7) * 256 + (blockIdx.x >> 3);   // batch-per-XCD (2048 blocks)
    int b = swz >> 8;
    int r0 = (swz & 255) * 16;         // first node row of this block
    int wid = tid >> 6, lane = tid & 63;
    int qt = lane >> 4, s16 = lane & 15;
    int row = wid * 4 + qt;            // 0..15, this quarter's node
    long long gnode = (long long)(b * N_ + r0 + row);
    const unsigned char* ybase = y1 + (long long)b * (N_ * F_) + s16 * 8;
    {
        const int4* ip = (const int4*)(sid2 + gnode * K_);
        int4 i0 = ip[0], i1 = ip[1], i2 = ip[2], i3 = ip[3];
        float cnt = (float)((i0.x >= 0) + (i0.y >= 0) + (i0.z >= 0) + (i0.w >= 0) +
                            (i1.x >= 0) + (i1.y >= 0) + (i1.z >= 0) + (i1.w >= 0) +
                            (i2.x >= 0) + (i2.y >= 0) + (i2.z >= 0) + (i2.w >= 0) +
                            (i3.x >= 0) + (i3.y >= 0) + (i3.z >= 0) + (i3.w >= 0));
        float a0 = 0.f, a1 = 0.f, a2 = 0.f, a3 = 0.f;
        float a4 = 0.f, a5 = 0.f, a6 = 0.f, a7 = 0.f;
#ifdef HW_FP8
        #define PROC(pk) { \
            float m = ((pk) >= 0) ? 1.0f : 0.0f; \
            int nid = (pk) < 0 ? 0 : (pk); \
            uint2 v = *(const uint2*)(ybase + (long long)nid * F_); \
            f32x2 c0 = __builtin_amdgcn_cvt_pk_f32_fp8(v.x, false); \
            f32x2 c1 = __builtin_amdgcn_cvt_pk_f32_fp8(v.x, true); \
            f32x2 c2 = __builtin_amdgcn_cvt_pk_f32_fp8(v.y, false); \
            f32x2 c3 = __builtin_amdgcn_cvt_pk_f32_fp8(v.y, true); \
            a0 += m * c0.x; a1 += m * c0.y; a2 += m * c1.x; a3 += m * c1.y; \
            a4 += m * c2.x; a5 += m * c2.y; a6 += m * c3.x; a7 += m * c3.y; }
#else
        #define PROC(pk) { \
            float ms = ((pk) >= 0) ? 0x1p120f : 0.0f; \
            int nid = (pk) < 0 ? 0 : (pk); \
            uint2 v = *(const uint2*)(ybase + (long long)nid * F_); \
            a0 += ms * DECM(v.x); a1 += ms * DECM(v.x >> 8); \
            a2 += ms * DECM(v.x >> 16); a3 += ms * DECM(v.x >> 24); \
            a4 += ms * DECM(v.y); a5 += ms * DECM(v.y >> 8); \
            a6 += ms * DECM(v.y >> 16); a7 += ms * DECM(v.y >> 24); }
#endif
        PROC(i0.x) PROC(i0.y) PROC(i0.z) PROC(i0.w)
        PROC(i1.x) PROC(i1.y) PROC(i1.z) PROC(i1.w)
        PROC(i2.x) PROC(i2.y) PROC(i2.z) PROC(i2.w)
        PROC(i3.x) PROC(i3.y) PROC(i3.z) PROC(i3.w)
        #undef PROC
        float inv = 1.0f / (cnt + 1e-8f);
        a0 *= inv; a1 *= inv; a2 *= inv; a3 *= inv;
        a4 *= inv; a5 *= inv; a6 *= inv; a7 *= inv;
        float* po = out + gnode * 384 + 128 + s16 * 8;
        *(f32x4*)po = (f32x4){a0, a1, a2, a3};
        *(f32x4*)(po + 4) = (f32x4){a4, a5, a6, a7};
        // x1 (bf16) into the 16x128 MFMA staging tile; chunk = s16
        int pch = s16 ^ (row & 15);
        short8 h;
        h[0] = (short)f2bf(a0); h[1] = (short)f2bf(a1);
        h[2] = (short)f2bf(a2); h[3] = (short)f2bf(a3);
        h[4] = (short)f2bf(a4); h[5] = (short)f2bf(a5);
        h[6] = (short)f2bf(a6); h[7] = (short)f2bf(a7);
        *(short8*)&xt[row * F_ + pch * 8] = h;
    }
    __syncthreads();
    if (wid != 0) return;              // waves 1-3 done (barrier already passed)
    // phase B: wave 0 transforms the 16 x1 rows -> y2
    int rr = lane & 15;
    short8 bfr[4];
    #pragma unroll
    for (int g = 0; g < 4; ++g) {
        int pch = (g * 4 + (lane >> 4)) ^ rr;
        bfr[g] = *(const short8*)&xt[rr * F_ + pch * 8];
    }
    int jq = (lane >> 4) * 4;
    long long ybyte = ((long long)(b * N_ + r0 + rr)) * F_;
    #pragma unroll
    for (int nt = 0; nt < 8; ++nt) {
        f32x4 acc = (f32x4){0.f, 0.f, 0.f, 0.f};
        #pragma unroll
        for (int g = 0; g < 4; ++g) {
            short8 afr = *(const short8*)(wf2 + ((nt * 4 + g) * 64 + lane) * 8);
            acc = __builtin_amdgcn_mfma_f32_16x16x32_bf16(afr, bfr[g], acc, 0, 0, 0);
        }
        float4 bv = *(const float4*)(bias + nt * 16 + jq);
        float t0 = fast_tanh(acc[0] + bv.x);
        float t1 = fast_tanh(acc[1] + bv.y);
        float t2 = fast_tanh(acc[2] + bv.z);
        float t3 = fast_tanh(acc[3] + bv.w);
        *(unsigned int*)(y2 + ybyte + nt * 16 + jq) = pack_fp8x4(t0, t1, t2, t3);
    }
}

// final agg: x2[b,n,:] = ( sum_k y2[b, sid2[n,k], :] ) / (cnt + eps)
// ONE node per 16-lane quarter; 16 independent 8B gathers in flight.
__global__ void __launch_bounds__(256) agg_kernel(
    const unsigned char* __restrict__ y, const int* __restrict__ sid2,
    float* __restrict__ out, int col_off) {
    int tid = threadIdx.x;
    int swz = (blockIdx.x & 7) * 256 + (blockIdx.x >> 3);   // batch-per-XCD
    int nodeblk = swz * 16;            // 16 nodes per block
    int wid = tid >> 6, lane = tid & 63;
    int qt = lane >> 4, s16 = lane & 15;
    int node = nodeblk + wid * 4 + qt;
    int b = node >> 12;                // N=4096
    const int4* ip = (const int4*)(sid2 + node * K_);
    int4 i0 = ip[0], i1 = ip[1], i2 = ip[2], i3 = ip[3];
    float cnt = (float)((i0.x >= 0) + (i0.y >= 0) + (i0.z >= 0) + (i0.w >= 0) +
                        (i1.x >= 0) + (i1.y >= 0) + (i1.z >= 0) + (i1.w >= 0) +
                        (i2.x >= 0) + (i2.y >= 0) + (i2.z >= 0) + (i2.w >= 0) +
                        (i3.x >= 0) + (i3.y >= 0) + (i3.z >= 0) + (i3.w >= 0));
    const unsigned char* ybase = y + (long long)b * (N_ * F_) + s16 * 8;
    float a0 = 0.f, a1 = 0.f, a2 = 0.f, a3 = 0.f;
    float a4 = 0.f, a5 = 0.f, a6 = 0.f, a7 = 0.f;
#ifdef HW_FP8
    #define PROC(pk) { \
        float m = ((pk) >= 0) ? 1.0f : 0.0f; \
        int nid = (pk) < 0 ? 0 : (pk); \
        uint2 v = *(const uint2*)(ybase + (long long)nid * F_); \
        f32x2 c0 = __builtin_amdgcn_cvt_pk_f32_fp8(v.x, false); \
        f32x2 c1 = __builtin_amdgcn_cvt_pk_f32_fp8(v.x, true); \
        f32x2 c2 = __builtin_amdgcn_cvt_pk_f32_fp8(v.y, false); \
        f32x2 c3 = __builtin_amdgcn_cvt_pk_f32_fp8(v.y, true); \
        a0 += m * c0.x; a1 += m * c0.y; a2 += m * c1.x; a3 += m * c1.y; \
        a4 += m * c2.x; a5 += m * c2.y; a6 += m * c3.x; a7 += m * c3.y; }
#else
    #define PROC(pk) { \
        float ms = ((pk) >= 0) ? 0x1p120f : 0.0f; \
        int nid = (pk) < 0 ? 0 : (pk); \
        uint2 v = *(const uint2*)(ybase + (long long)nid * F_); \
        a0 += ms * DECM(v.x); a1 += ms * DECM(v.x >> 8); \
        a2 += ms * DECM(v.x >> 16); a3 += ms * DECM(v.x >> 24); \
        a4 += ms * DECM(v.y); a5 += ms * DECM(v.y >> 8); \
        a6 += ms * DECM(v.y >> 16); a7 += ms * DECM(v.y >> 24); }
#endif
    PROC(i0.x) PROC(i0.y) PROC(i0.z) PROC(i0.w)
    PROC(i1.x) PROC(i1.y) PROC(i1.z) PROC(i1.w)
    PROC(i2.x) PROC(i2.y) PROC(i2.z) PROC(i2.w)
    PROC(i3.x) PROC(i3.y) PROC(i3.z) PROC(i3.w)
    #undef PROC
    float inv = 1.0f / (cnt + 1e-8f);
    a0 *= inv; a1 *= inv; a2 *= inv; a3 *= inv;
    a4 *= inv; a5 *= inv; a6 *= inv; a7 *= inv;
    float* po = out + (long long)node * 384 + col_off + s16 * 8;
    *(f32x4*)po = (f32x4){a0, a1, a2, a3};
    *(f32x4*)(po + 4) = (f32x4){a4, a5, a6, a7};
}

extern "C" void kernel_launch(void* const* d_in, const int* in_sizes, int n_in,
                              void* d_out, int out_size, void* d_ws, size_t ws_size,
                              hipStream_t stream) {
    const float* x0        = (const float*)d_in[0];
    const int*   edges_raw = (const int*)d_in[1];
    const int*   ne_raw    = (const int*)d_in[2];
    const int*   mask      = (const int*)d_in[3];
    const float* W1        = (const float*)d_in[4];
    const float* b1        = (const float*)d_in[5];
    const float* W2        = (const float*)d_in[6];
    const float* b2        = (const float*)d_in[7];
    float* out = (float*)d_out;
    char* ws = (char*)d_ws;

    unsigned char*  y1   = (unsigned char*)ws;                    // B*N*F fp8 = 4 MB
    unsigned char*  y2   = (unsigned char*)(ws + 4194304);        // B*N*F fp8 = 4 MB
    unsigned short* wf   = (unsigned short*)(ws + 8388608);       // 2*128*128 = 64 KB
    int* flags           = (int*)(ws + 8454144);                  // 2 x int32
    int* sid2            = (int*)(ws + 8519680);                  // B*N*K     = 2 MB

    wprep<<<17, 256, 0, stream>>>(W1, W2, edges_raw, ne_raw, wf, flags);
    // round 1: dense node transform (+ x0 copy + sid2 pack)
    node_kernel<<<512, 256, 0, stream>>>(x0, edges_raw, ne_raw, mask,
                                         flags, wf, b1, y1, out, sid2);
    // fused agg1+node2, high-TLP shape (2048 blocks, 16 nodes each)
    aggnode_kernel<<<2048, 256, 0, stream>>>(y1, sid2, wf + 16384, b2, out, y2);
    // final aggregation
    agg_kernel<<<2048, 256, 0, stream>>>(y2, sid2, out, 256);
}